// Round 9
// baseline (13070.772 us; speedup 1.0000x reference)
//
#include <hip/hip_runtime.h>
#include <stdint.h>

// B=512, S=512, F=64, H=128, 4H=512, O=64
#define SEQ 512
#define HID 128
#define HR 64            // hseq ring depth (steps), L2-resident

typedef short bf16x8 __attribute__((ext_vector_type(8)));
typedef float f32x4v __attribute__((ext_vector_type(4)));

#define MFMA16(a, b, c) __builtin_amdgcn_mfma_f32_16x16x32_bf16((a), (b), (c), 0, 0, 0)

__device__ __forceinline__ uint32_t bfr(float f) {
    uint32_t u = __float_as_uint(f);
    return (u + 0x7fffu + ((u >> 16) & 1u)) >> 16;
}
__device__ __forceinline__ uint32_t bfp(float a, float b) { return bfr(a) | (bfr(b) << 16); }
__device__ __forceinline__ float fsig(float x) {
    return __builtin_amdgcn_rcpf(1.0f + __expf(-x));
}
__device__ __forceinline__ float ftanh(float x) {
    return 1.0f - 2.0f * __builtin_amdgcn_rcpf(__expf(2.0f * x) + 1.0f);
}

__device__ __forceinline__ bf16x8 afrag(const float* W, int row, int K, int k0) {
    const float4* p = (const float4*)(W + (size_t)row * K + k0);
    float4 a = p[0], b = p[1];
    union { bf16x8 v; uint32_t u[4]; } f;
    f.u[0] = bfp(a.x, a.y); f.u[1] = bfp(a.z, a.w);
    f.u[2] = bfp(b.x, b.y); f.u[3] = bfp(b.z, b.w);
    return f.v;
}

// stage 4 fp32 x as bf16 hi (off 0) + residual lo (off 2048), swizzled row xrb
__device__ __forceinline__ void stage_x4(uint8_t* dst, int xrb, int xf0, float4 v) {
    uint32_t h0 = bfr(v.x), h1 = bfr(v.y), h2 = bfr(v.z), h3 = bfr(v.w);
    float r0 = v.x - __uint_as_float(h0 << 16), r1 = v.y - __uint_as_float(h1 << 16);
    float r2 = v.z - __uint_as_float(h2 << 16), r3 = v.w - __uint_as_float(h3 << 16);
    int kb = (2 * xf0) ^ ((xrb & 7) << 4);
    *(uint2*)(dst + xrb * 128 + kb) = make_uint2(h0 | (h1 << 16), h2 | (h3 << 16));
    *(uint2*)(dst + 2048 + xrb * 128 + kb) = make_uint2(bfp(r0, r1), bfp(r2, r3));
}

// all-thread acquire spin (bounded: on cap, proceed -> visible absmax fail, no hang)
__device__ __forceinline__ void wait1(const int* f, int v) {
    if (v <= 0) return;
    for (long c = 0; c < 30000000L; ++c) {
        if (__hip_atomic_load(f, __ATOMIC_ACQUIRE, __HIP_MEMORY_SCOPE_AGENT) >= v) return;
        __builtin_amdgcn_s_sleep(8);
    }
}
__device__ __forceinline__ void wait3(const int* fa, int va, const int* fb, int vb,
                                      const int* fc, int vc) {
    for (long c = 0; c < 30000000L; ++c) {
        int a = (va > 0) ? __hip_atomic_load(fa, __ATOMIC_ACQUIRE, __HIP_MEMORY_SCOPE_AGENT) : 0;
        int b = (vb > 0) ? __hip_atomic_load(fb, __ATOMIC_ACQUIRE, __HIP_MEMORY_SCOPE_AGENT) : 0;
        int d = (vc > 0) ? __hip_atomic_load(fc, __ATOMIC_ACQUIRE, __HIP_MEMORY_SCOPE_AGENT) : 0;
        if (a >= va && b >= vb && d >= vc) return;
        __builtin_amdgcn_s_sleep(8);
    }
}
// all-stores-drained -> barrier -> L2 writeback -> release flag (R8-validated protocol)
__device__ __forceinline__ void publish(int* f, int v, int tid) {
    asm volatile("s_waitcnt vmcnt(0) lgkmcnt(0)" ::: "memory");
    __syncthreads();
    if (tid == 0) {
        __threadfence();
        __hip_atomic_store(f, v, __ATOMIC_RELEASE, __HIP_MEMORY_SCOPE_AGENT);
    }
}

// hseq RING granule (bf16): g = (t%HR)*8192 + m*256 + jblk*16 + b ; elems g*8+ji
// xch ring elem: m*8192 + slot*2048 + half*1024 + b*64 + j_local   (per layer)

// ===================== L0 j-half =====================
__device__ __forceinline__ void l0_half(
    uint8_t* lds, int m, int half,
    const float* __restrict__ x, const float* __restrict__ Wih,
    const float* __restrict__ Whh, const float* __restrict__ bih,
    const float* __restrict__ bhh, unsigned short* hseq,
    unsigned short* xch, int* flags)
{
    const int tid = threadIdx.x, wid = tid >> 6, lane = tid & 63;
    const int l15 = lane & 15, lg = lane >> 4;
    const int bb = m * 16, jbl = wid * 16;
    const int j0g = half * 64 + jbl + lg * 4;

    uint8_t* hbuf = lds;            // 2 x 4096: full h rows (own+imported), swizzled
    uint8_t* xbuf = lds + 8192;     // 2 x 4096: x hi/lo

    int* own_flag = flags + 2 * m + half;
    const int* par_flag = flags + 2 * m + (half ^ 1);
    const int* dnA = flags + 64 + 2 * m;
    const int* dnB = flags + 64 + 2 * m + 1;
    unsigned short* xch_own = xch + (size_t)m * 8192 + half * 1024;
    const unsigned short* xch_par = xch + (size_t)m * 8192 + (half ^ 1) * 1024;

    bf16x8 wih[4][2], whh[4][4];
    f32x4v bias[4];
#pragma unroll
    for (int c = 0; c < 4; c++) {
        int row = c * 128 + half * 64 + jbl + l15;
#pragma unroll
        for (int kt = 0; kt < 2; kt++) wih[c][kt] = afrag(Wih, row, 64, kt * 32 + lg * 8);
#pragma unroll
        for (int kt = 0; kt < 4; kt++) whh[c][kt] = afrag(Whh, row, 128, kt * 32 + lg * 8);
#pragma unroll
        for (int e = 0; e < 4; e++) {
            int gr = c * 128 + half * 64 + jbl + lg * 4 + e;
            bias[c][e] = bih[gr] + bhh[gr];
        }
    }

    const int xrb = tid >> 4, xf0 = (tid & 15) * 4;
    const size_t xbase = (size_t)(bb + xrb) * SEQ * 64 + xf0;
    const int swz = (l15 & 7) << 4;

    // zero hbuf (both slots), stage x(0)->slot0
    *(f32x4v*)(lds + tid * 32) = f32x4v{0.f, 0.f, 0.f, 0.f};
    *(f32x4v*)(lds + tid * 32 + 16) = f32x4v{0.f, 0.f, 0.f, 0.f};
    stage_x4(xbuf, xrb, xf0, *(const float4*)(x + xbase));
    __syncthreads();
    // acc(0) = bias + Wih@x(0)
    f32x4v acc[4];
    {
        bf16x8 xhf[2], xlf[2];
#pragma unroll
        for (int kt = 0; kt < 2; kt++) {
            int kb = (2 * (kt * 32 + lg * 8)) ^ swz;
            xhf[kt] = *(const bf16x8*)(xbuf + l15 * 128 + kb);
            xlf[kt] = *(const bf16x8*)(xbuf + 2048 + l15 * 128 + kb);
        }
#pragma unroll
        for (int c = 0; c < 4; c++) {
            f32x4v a = MFMA16(wih[c][0], xhf[0], bias[c]);
            a = MFMA16(wih[c][1], xhf[1], a);
            a = MFMA16(wih[c][0], xlf[0], a);
            a = MFMA16(wih[c][1], xlf[1], a);
            acc[c] = a;
        }
    }
    stage_x4(xbuf + 4096, xrb, xf0, *(const float4*)(x + xbase + 64));
    __syncthreads();

    float cst[4] = {0.f, 0.f, 0.f, 0.f};
    const int hwb = l15 * 256 + ((2 * j0g) ^ ((l15 & 7) << 4));
    const int imp_rb = tid >> 4, imp_jl = (tid & 15) * 4;
    const int imp_pj = (half ^ 1) * 64 + imp_jl;
    const int imp_wb = imp_rb * 256 + ((2 * imp_pj) ^ ((imp_rb & 7) << 4));
    uint2 pimp = make_uint2(0, 0);

    for (int t = 0; t < SEQ; t++) {
        const int p = t & 1;
        if (t > 0) *(uint2*)(hbuf + p * 4096 + imp_wb) = pimp;   // partner h(t-1)
        asm volatile("s_waitcnt lgkmcnt(0)\n\ts_barrier" ::: "memory");

        bf16x8 hf[4];
#pragma unroll
        for (int kt = 0; kt < 4; kt++) {
            int kb = (2 * (kt * 32 + lg * 8)) ^ swz;
            hf[kt] = *(const bf16x8*)(hbuf + p * 4096 + l15 * 256 + kb);
        }
        float4 xv = {0.f, 0.f, 0.f, 0.f};
        if (t + 2 < SEQ) xv = *(const float4*)(x + xbase + (size_t)(t + 2) * 64);
        bf16x8 xhf[2], xlf[2];
#pragma unroll
        for (int kt = 0; kt < 2; kt++) {
            int kb = (2 * (kt * 32 + lg * 8)) ^ swz;
            xhf[kt] = *(const bf16x8*)(xbuf + (p ^ 1) * 4096 + l15 * 128 + kb);
            xlf[kt] = *(const bf16x8*)(xbuf + (p ^ 1) * 4096 + 2048 + l15 * 128 + kb);
        }
        // guards: partner consumed xch slot t&3 (>= t-2); L1 consumed hseq slot t%HR (>= t-HR+1)
        wait3(par_flag, t - 2, dnA, t - (HR - 1), dnB, t - (HR - 1));

        f32x4v g4[4];
#pragma unroll
        for (int c = 0; c < 4; c++) {
            f32x4v a = MFMA16(whh[c][0], hf[0], acc[c]);
#pragma unroll
            for (int kt = 1; kt < 4; kt++) a = MFMA16(whh[c][kt], hf[kt], a);
            g4[c] = a;
        }
        f32x4v accn[4];
#pragma unroll
        for (int c = 0; c < 4; c++) {
            f32x4v a = MFMA16(wih[c][0], xhf[0], bias[c]);
            a = MFMA16(wih[c][1], xhf[1], a);
            a = MFMA16(wih[c][0], xlf[0], a);
            a = MFMA16(wih[c][1], xlf[1], a);
            accn[c] = a;
        }

        float h[4];
#pragma unroll
        for (int e = 0; e < 4; e++) {
            float ig = fsig(g4[0][e]);
            float fg = fsig(g4[1][e]);
            float gg = ftanh(g4[2][e]);
            float og = fsig(g4[3][e]);
            float cv = fg * cst[e] + ig * gg;
            cst[e] = cv;
            h[e] = og * ftanh(cv);
        }
        uint32_t hp0 = bfp(h[0], h[1]), hp1 = bfp(h[2], h[3]);
        *(uint2*)(hbuf + (p ^ 1) * 4096 + hwb) = make_uint2(hp0, hp1);
        int gidx = ((((t & (HR - 1)) * 32 + m) * 16 + (j0g >> 3)) * 16 + l15) * 8 + (j0g & 7);
        *(uint2*)(hseq + gidx) = make_uint2(hp0, hp1);
        *(uint2*)(xch_own + (size_t)(t & 3) * 2048 + l15 * 64 + jbl + lg * 4) = make_uint2(hp0, hp1);
        if (t + 2 < SEQ) stage_x4(xbuf + p * 4096, xrb, xf0, xv);

        publish(own_flag, t + 1, tid);
        if (t + 1 < SEQ) {
            wait1(par_flag, t + 1);
            pimp = *(const uint2*)(xch_par + (size_t)(t & 3) * 2048 + imp_rb * 64 + imp_jl);
        }
#pragma unroll
        for (int c = 0; c < 4; c++) acc[c] = accn[c];
    }
}

// ===================== L1 j-half (+FC on half A) =====================
__device__ __forceinline__ void l1_half(
    uint8_t* lds, int m, int half,
    const unsigned short* hseq, const float* __restrict__ Wih,
    const float* __restrict__ Whh, const float* __restrict__ bih,
    const float* __restrict__ bhh, const float* __restrict__ fcw,
    const float* __restrict__ fcb, unsigned short* xch,
    float* hfin_g, int* flags, float* __restrict__ out)
{
    const int tid = threadIdx.x, wid = tid >> 6, lane = tid & 63;
    const int l15 = lane & 15, lg = lane >> 4;
    const int bb = m * 16, jbl = wid * 16;
    const int j0g = half * 64 + jbl + lg * 4;

    uint8_t* hbuf = lds;   // 2 x 4096 h1 rows

    int* own_flag = flags + 64 + 2 * m + half;
    const int* par_flag = flags + 64 + 2 * m + (half ^ 1);
    const int* upA = flags + 2 * m;
    const int* upB = flags + 2 * m + 1;
    unsigned short* xch_own = xch + (size_t)m * 8192 + half * 1024;
    const unsigned short* xch_par = xch + (size_t)m * 8192 + (half ^ 1) * 1024;

    bf16x8 wih[4][4], whh[4][4];
    f32x4v bias[4];
#pragma unroll
    for (int c = 0; c < 4; c++) {
        int row = c * 128 + half * 64 + jbl + l15;
#pragma unroll
        for (int kt = 0; kt < 4; kt++) {
            wih[c][kt] = afrag(Wih, row, 128, kt * 32 + lg * 8);
            whh[c][kt] = afrag(Whh, row, 128, kt * 32 + lg * 8);
        }
#pragma unroll
        for (int e = 0; e < 4; e++) {
            int gr = c * 128 + half * 64 + jbl + lg * 4 + e;
            bias[c][e] = bih[gr] + bhh[gr];
        }
    }
    const int swz = (l15 & 7) << 4;

    *(f32x4v*)(lds + tid * 32) = f32x4v{0.f, 0.f, 0.f, 0.f};
    *(f32x4v*)(lds + tid * 32 + 16) = f32x4v{0.f, 0.f, 0.f, 0.f};
    __syncthreads();

    // prologue: h0(0) frags
    wait3(upA, 1, upB, 1, upA, 1);
    bf16x8 h0c[4];
#pragma unroll
    for (int kt = 0; kt < 4; kt++)
        h0c[kt] = *(const bf16x8*)(hseq + ((size_t)((0 * 32 + m) * 16 + kt * 4 + lg) * 16 + l15) * 8);

    float cst[4] = {0.f, 0.f, 0.f, 0.f};
    const int hwb = l15 * 256 + ((2 * j0g) ^ ((l15 & 7) << 4));
    const int imp_rb = tid >> 4, imp_jl = (tid & 15) * 4;
    const int imp_pj = (half ^ 1) * 64 + imp_jl;
    const int imp_wb = imp_rb * 256 + ((2 * imp_pj) ^ ((imp_rb & 7) << 4));
    uint2 pimp = make_uint2(0, 0);

    for (int t = 0; t < SEQ; t++) {
        const int p = t & 1;
        if (t > 0) *(uint2*)(hbuf + p * 4096 + imp_wb) = pimp;   // partner h1(t-1)
        asm volatile("s_waitcnt lgkmcnt(0)\n\ts_barrier" ::: "memory");

        bf16x8 hf[4];
#pragma unroll
        for (int kt = 0; kt < 4; kt++) {
            int kb = (2 * (kt * 32 + lg * 8)) ^ swz;
            hf[kt] = *(const bf16x8*)(hbuf + p * 4096 + l15 * 256 + kb);
        }
        wait1(par_flag, t - 2);   // xch slot reuse guard

        f32x4v g4[4];
#pragma unroll
        for (int c = 0; c < 4; c++) {
            f32x4v a = MFMA16(wih[c][0], h0c[0], bias[c]);
#pragma unroll
            for (int kt = 1; kt < 4; kt++) a = MFMA16(wih[c][kt], h0c[kt], a);
#pragma unroll
            for (int kt = 0; kt < 4; kt++) a = MFMA16(whh[c][kt], hf[kt], a);
            g4[c] = a;
        }

        float h[4];
#pragma unroll
        for (int e = 0; e < 4; e++) {
            float ig = fsig(g4[0][e]);
            float fg = fsig(g4[1][e]);
            float gg = ftanh(g4[2][e]);
            float og = fsig(g4[3][e]);
            float cv = fg * cst[e] + ig * gg;
            cst[e] = cv;
            h[e] = og * ftanh(cv);
        }
        uint32_t hp0 = bfp(h[0], h[1]), hp1 = bfp(h[2], h[3]);
        *(uint2*)(hbuf + (p ^ 1) * 4096 + hwb) = make_uint2(hp0, hp1);
        *(uint2*)(xch_own + (size_t)(t & 3) * 2048 + l15 * 64 + jbl + lg * 4) = make_uint2(hp0, hp1);
        if (t == SEQ - 1)
            *(f32x4v*)(hfin_g + m * 2048 + l15 * 128 + j0g) = f32x4v{h[0], h[1], h[2], h[3]};

        publish(own_flag, t + 1, tid);
        if (t + 1 < SEQ) {
            wait3(par_flag, t + 1, upA, t + 2, upB, t + 2);
            pimp = *(const uint2*)(xch_par + (size_t)(t & 3) * 2048 + imp_rb * 64 + imp_jl);
            const int ts = (t + 1) & (HR - 1);
#pragma unroll
            for (int kt = 0; kt < 4; kt++)
                h0c[kt] = *(const bf16x8*)(hseq + ((size_t)((ts * 32 + m) * 16 + kt * 4 + lg) * 16 + l15) * 8);
        }
    }

    // FC on half A: out[b][o] = relu(h1).fcw[o] + fcb[o]
    if (half == 0) {
        wait1(par_flag, SEQ);    // partner hfin drained+published
        const int b = tid >> 4, o0 = (tid & 15) * 4;
        const float* hrow = hfin_g + m * 2048 + b * 128;
        const float4* h4 = (const float4*)hrow;
#pragma unroll
        for (int oo = 0; oo < 4; oo++) {
            int o = o0 + oo;
            float a = fcb[o];
            const float4* w4 = (const float4*)(fcw + o * HID);
            for (int k = 0; k < 32; k++) {
                float4 hv = h4[k], wv = w4[k];
                a += fmaxf(hv.x, 0.f) * wv.x + fmaxf(hv.y, 0.f) * wv.y +
                     fmaxf(hv.z, 0.f) * wv.z + fmaxf(hv.w, 0.f) * wv.w;
            }
            out[(bb + b) * 64 + o] = a;
        }
    }
}

// ============ 128 blocks x 256 thr: [0,32)=L0A [32,64)=L0B [64,96)=L1A [96,128)=L1B ============
__global__ __launch_bounds__(256, 1) void lstm_split(
    const float* __restrict__ x,
    const float* __restrict__ Wih0, const float* __restrict__ Whh0,
    const float* __restrict__ bih0, const float* __restrict__ bhh0,
    const float* __restrict__ Wih1, const float* __restrict__ Whh1,
    const float* __restrict__ bih1, const float* __restrict__ bhh1,
    const float* __restrict__ fcw, const float* __restrict__ fcb,
    int* flags, unsigned short* xch0, unsigned short* xch1,
    unsigned short* hseq, float* hfin_g, float* __restrict__ out)
{
    __shared__ __align__(16) uint8_t lds[16384];
    const int bid = blockIdx.x;
    const int m = bid & 31, grp = bid >> 5;
    if (grp == 0)      l0_half(lds, m, 0, x, Wih0, Whh0, bih0, bhh0, hseq, xch0, flags);
    else if (grp == 1) l0_half(lds, m, 1, x, Wih0, Whh0, bih0, bhh0, hseq, xch0, flags);
    else if (grp == 2) l1_half(lds, m, 0, hseq, Wih1, Whh1, bih1, bhh1, fcw, fcb, xch1, hfin_g, flags, out);
    else               l1_half(lds, m, 1, hseq, Wih1, Whh1, bih1, bhh1, fcw, fcb, xch1, hfin_g, flags, out);
}

extern "C" void kernel_launch(void* const* d_in, const int* in_sizes, int n_in,
                              void* d_out, int out_size, void* d_ws, size_t ws_size,
                              hipStream_t stream) {
    const float* x    = (const float*)d_in[0];
    const float* Wih0 = (const float*)d_in[1];
    const float* Whh0 = (const float*)d_in[2];
    const float* bih0 = (const float*)d_in[3];
    const float* bhh0 = (const float*)d_in[4];
    const float* Wih1 = (const float*)d_in[5];
    const float* Whh1 = (const float*)d_in[6];
    const float* bih1 = (const float*)d_in[7];
    const float* bhh1 = (const float*)d_in[8];
    const float* fcw  = (const float*)d_in[9];
    const float* fcb  = (const float*)d_in[10];

    // ws map (total ~10 MB, safely under proven 64 MB floor):
    //   [0,512): flags[128]   [4K,260K): hfin_g 32x16x128 f32
    //   [512K,1M): xch0       [1M,1.5M): xch1      [2M,10M): hseq ring (HR=64)
    char* ws = (char*)d_ws;
    int* flags = (int*)ws;
    float* hfin_g = (float*)(ws + 4096);
    unsigned short* xch0 = (unsigned short*)(ws + (512 << 10));
    unsigned short* xch1 = (unsigned short*)(ws + (1 << 20));
    unsigned short* hseq = (unsigned short*)(ws + (2 << 20));
    hipMemsetAsync(d_ws, 0, 512, stream);

    lstm_split<<<128, 256, 0, stream>>>(x, Wih0, Whh0, bih0, bhh0,
                                        Wih1, Whh1, bih1, bhh1, fcw, fcb,
                                        flags, xch0, xch1, hseq, hfin_g, (float*)d_out);
}

// Round 10
// 749.929 us; speedup vs baseline: 17.4293x; 17.4293x over previous
//
#include <hip/hip_runtime.h>
#include <stdint.h>

// B=512, S=512, F=64, H=128, 4H=512, O=64
#define SEQ 512
#define HID 128
#define CH 8             // pipeline chunk (steps) ; NCHUNK = 64

typedef short bf16x8 __attribute__((ext_vector_type(8)));   // 8 bf16 = 4 VGPR
typedef float f32x4v __attribute__((ext_vector_type(4)));   // MFMA acc

#define MFMA16(a, b, c) __builtin_amdgcn_mfma_f32_16x16x32_bf16((a), (b), (c), 0, 0, 0)

__device__ __forceinline__ uint32_t bfr(float f) {          // fp32 -> bf16 (RNE)
    uint32_t u = __float_as_uint(f);
    return (u + 0x7fffu + ((u >> 16) & 1u)) >> 16;
}
__device__ __forceinline__ uint32_t bfp(float a, float b) { // pack 2 bf16
    return bfr(a) | (bfr(b) << 16);
}
__device__ __forceinline__ float fsig(float x) {
    return __builtin_amdgcn_rcpf(1.0f + __expf(-x));
}
__device__ __forceinline__ float ftanh(float x) {
    return 1.0f - 2.0f * __builtin_amdgcn_rcpf(__expf(2.0f * x) + 1.0f);
}

// A-fragment: lane holds W[row][k0 .. k0+7] as bf16x8 (row = base + lane&15).
__device__ __forceinline__ bf16x8 afrag(const float* W, int row, int K, int k0) {
    const float4* p = (const float4*)(W + (size_t)row * K + k0);
    float4 a = p[0], b = p[1];
    union { bf16x8 v; uint32_t u[4]; } f;
    f.u[0] = bfp(a.x, a.y); f.u[1] = bfp(a.z, a.w);
    f.u[2] = bfp(b.x, b.y); f.u[3] = bfp(b.z, b.w);
    return f.v;
}

// stage 2 fp32 x-values as bf16 hi (offset 0) + residual lo (offset 2048), swizzled
__device__ __forceinline__ void stage_x(uint8_t* dst, int xrb, int xf0, float2 v) {
    uint32_t hx = bfr(v.x), hy = bfr(v.y);
    float rx = v.x - __uint_as_float(hx << 16);
    float ry = v.y - __uint_as_float(hy << 16);
    int kb = (2 * xf0) ^ ((xrb & 7) << 4);
    *(uint32_t*)(dst + xrb * 128 + kb) = hx | (hy << 16);
    *(uint32_t*)(dst + 2048 + xrb * 128 + kb) = bfr(rx) | (bfr(ry) << 16);
}

// consumer-side chunk gate: tid0 acquire-spins, block joins at barrier
__device__ __forceinline__ void wait_flag(int* flags, int src, int need, int tid) {
    if (tid == 0) {
        for (long c = 0; c < 200000000L; ++c) {
            int v = __hip_atomic_load(flags + src, __ATOMIC_ACQUIRE,
                                      __HIP_MEMORY_SCOPE_AGENT);
            if (v >= need) break;
            __builtin_amdgcn_s_sleep(2);
        }
    }
    __syncthreads();
}

// hseq granule layout (bf16): granule g = t*8192 + bblk*256 + jblk*16 + b, elems g*8+ji

// =============== L0 role: gates(t)=[carried Wih@x(t)]+Whh@h(t); publish chunks ===============
__device__ __forceinline__ void l0_body(
    uint8_t* lds, const float* __restrict__ x, const float* __restrict__ Wih,
    const float* __restrict__ Whh, const float* __restrict__ bih,
    const float* __restrict__ bhh, unsigned short* __restrict__ hseq, int* flags)
{
    const int tid = threadIdx.x, wid = tid >> 6, lane = tid & 63;
    const int l15 = lane & 15, lg = lane >> 4;
    const int bblk = blockIdx.x, bb = bblk * 16, jb = wid * 16;

    uint8_t* hbuf = lds;            // 2 x 4096 h dbuf (bf16, swizzled)
    uint8_t* xbuf = lds + 8192;     // 2 par x (hi 2KB + lo 2KB)

    bf16x8 wih[4][2], whh[4][4];
    f32x4v bias[4];
#pragma unroll
    for (int c = 0; c < 4; c++) {
        int row = c * 128 + jb + l15;
#pragma unroll
        for (int kt = 0; kt < 2; kt++) wih[c][kt] = afrag(Wih, row, 64, kt * 32 + lg * 8);
#pragma unroll
        for (int kt = 0; kt < 4; kt++) whh[c][kt] = afrag(Whh, row, 128, kt * 32 + lg * 8);
#pragma unroll
        for (int e = 0; e < 4; e++) {
            int gr = c * 128 + jb + lg * 4 + e;
            bias[c][e] = bih[gr] + bhh[gr];
        }
    }

    const int xrb = tid >> 5, xf0 = (tid & 31) * 2;
    const size_t xbase = (size_t)(bb + xrb) * SEQ * 64 + xf0;
    const int swz = (l15 & 7) << 4;

    *(f32x4v*)(lds + tid * 16) = f32x4v{0.f, 0.f, 0.f, 0.f};  // zero hbuf 8KB
    stage_x(xbuf, xrb, xf0, *(const float2*)(x + xbase));
    __syncthreads();
    f32x4v acc[4];
    {
        bf16x8 xhf[2], xlf[2];
#pragma unroll
        for (int kt = 0; kt < 2; kt++) {
            int kb = (2 * (kt * 32 + lg * 8)) ^ swz;
            xhf[kt] = *(const bf16x8*)(xbuf + l15 * 128 + kb);
            xlf[kt] = *(const bf16x8*)(xbuf + 2048 + l15 * 128 + kb);
        }
#pragma unroll
        for (int c = 0; c < 4; c++) {
            f32x4v a = MFMA16(wih[c][0], xhf[0], bias[c]);
            a = MFMA16(wih[c][1], xhf[1], a);
            a = MFMA16(wih[c][0], xlf[0], a);
            a = MFMA16(wih[c][1], xlf[1], a);
            acc[c] = a;
        }
    }
    stage_x(xbuf + 4096, xrb, xf0, *(const float2*)(x + xbase + 64));
    __syncthreads();

    float cst[4] = {0.f, 0.f, 0.f, 0.f};
    const int j0 = jb + lg * 4;
    const int hwb = l15 * 256 + ((2 * j0) ^ ((l15 & 7) << 4));

    for (int t = 0; t < SEQ; t++) {
        const int p = t & 1;
        const uint8_t* hb = hbuf + p * 4096;
        bf16x8 hf[4];
#pragma unroll
        for (int kt = 0; kt < 4; kt++) {
            int kb = (2 * (kt * 32 + lg * 8)) ^ swz;
            hf[kt] = *(const bf16x8*)(hb + l15 * 256 + kb);
        }
        float2 xv = {0.f, 0.f};
        if (t + 2 < SEQ) xv = *(const float2*)(x + xbase + (size_t)(t + 2) * 64);
        const uint8_t* xh = xbuf + (p ^ 1) * 4096;
        bf16x8 xhf[2], xlf[2];
#pragma unroll
        for (int kt = 0; kt < 2; kt++) {
            int kb = (2 * (kt * 32 + lg * 8)) ^ swz;
            xhf[kt] = *(const bf16x8*)(xh + l15 * 128 + kb);
            xlf[kt] = *(const bf16x8*)(xh + 2048 + l15 * 128 + kb);
        }

        // 8 interleaved MFMA chains (4 on-path g4 + 4 off-path accn), kt-outer:
        // dependency distance ~8 MFMAs > latency -> no issue stall on the chain.
        f32x4v g4[4], accn[4];
#pragma unroll
        for (int kt = 0; kt < 4; kt++) {
            const bf16x8 xa = (kt < 2) ? xhf[kt] : xlf[kt - 2];
#pragma unroll
            for (int c = 0; c < 4; c++)
                g4[c] = MFMA16(whh[c][kt], hf[kt], kt == 0 ? acc[c] : g4[c]);
#pragma unroll
            for (int c = 0; c < 4; c++)
                accn[c] = MFMA16(wih[c][kt & 1], xa, kt == 0 ? bias[c] : accn[c]);
        }

        float h[4];
#pragma unroll
        for (int e = 0; e < 4; e++) {
            float ig = fsig(g4[0][e]);
            float fg = fsig(g4[1][e]);
            float gg = ftanh(g4[2][e]);
            float og = fsig(g4[3][e]);
            float cv = fg * cst[e] + ig * gg;
            cst[e] = cv;
            h[e] = og * ftanh(cv);
        }
        uint32_t hp0 = bfp(h[0], h[1]), hp1 = bfp(h[2], h[3]);
        *(uint2*)(hbuf + (p ^ 1) * 4096 + hwb) = make_uint2(hp0, hp1);
        int gidx = (((t * 32 + bblk) * 16 + (j0 >> 3)) * 16 + l15) * 8 + (j0 & 7);
        *(uint2*)(hseq + gidx) = make_uint2(hp0, hp1);

        if (t + 2 < SEQ) stage_x(xbuf + p * 4096, xrb, xf0, xv);

        asm volatile("s_waitcnt lgkmcnt(0)\n\ts_barrier" ::: "memory");

        // publish chunk: all stores drained -> barrier -> L2 writeback -> release flag
        if (((t + 1) & (CH - 1)) == 0) {
            asm volatile("s_waitcnt vmcnt(0)" ::: "memory");
            __syncthreads();
            if (tid == 0) {
                __threadfence();
                __hip_atomic_store(flags + bblk, (t + 1) / CH, __ATOMIC_RELEASE,
                                   __HIP_MEMORY_SCOPE_AGENT);
            }
        }
#pragma unroll
        for (int c = 0; c < 4; c++) acc[c] = accn[c];
    }
}

// =============== L1 role + FC: gates(t)=[carried Wih@h0(t)]+Whh@h1(t) ===============
__device__ __forceinline__ void l1_body(
    uint8_t* lds, const unsigned short* __restrict__ hseq,
    const float* __restrict__ Wih, const float* __restrict__ Whh,
    const float* __restrict__ bih, const float* __restrict__ bhh,
    const float* __restrict__ fcw, const float* __restrict__ fcb,
    float* __restrict__ out, int* flags)
{
    const int tid = threadIdx.x, wid = tid >> 6, lane = tid & 63;
    const int l15 = lane & 15, lg = lane >> 4;
    const int bblk = blockIdx.x - 32, bb = bblk * 16, jb = wid * 16;

    float* hfin = (float*)(lds + 8192);

    bf16x8 wih[4][4], whh[4][4];
    f32x4v bias[4];
#pragma unroll
    for (int c = 0; c < 4; c++) {
        int row = c * 128 + jb + l15;
#pragma unroll
        for (int kt = 0; kt < 4; kt++) {
            wih[c][kt] = afrag(Wih, row, 128, kt * 32 + lg * 8);
            whh[c][kt] = afrag(Whh, row, 128, kt * 32 + lg * 8);
        }
#pragma unroll
        for (int e = 0; e < 4; e++) {
            int gr = c * 128 + jb + lg * 4 + e;
            bias[c][e] = bih[gr] + bhh[gr];
        }
    }

    const int swz = (l15 & 7) << 4;
    // h0 granule for (t,kt): t*8192 + bblk*256 + (kt*4+lg)*16 + l15
    const size_t gbase = (size_t)bblk * 256 + lg * 16 + l15;

    wait_flag(flags, bblk, 2, tid);          // h0 steps 0..15 available

    f32x4v acc[4];
    {
        bf16x8 f0[4];
#pragma unroll
        for (int kt = 0; kt < 4; kt++)
            f0[kt] = *(const bf16x8*)(hseq + (gbase + kt * 64) * 8);
#pragma unroll
        for (int c = 0; c < 4; c++) {
            f32x4v a = MFMA16(wih[c][0], f0[0], bias[c]);
#pragma unroll
            for (int kt = 1; kt < 4; kt++) a = MFMA16(wih[c][kt], f0[kt], a);
            acc[c] = a;
        }
    }
    bf16x8 h0A[4], h0B[4];
#pragma unroll
    for (int kt = 0; kt < 4; kt++)
        h0A[kt] = *(const bf16x8*)(hseq + (gbase + (size_t)1 * 8192 + kt * 64) * 8);

    *(f32x4v*)(lds + tid * 16) = f32x4v{0.f, 0.f, 0.f, 0.f};   // zero h1 dbuf
    __syncthreads();

    float cst[4] = {0.f, 0.f, 0.f, 0.f};
    const int j0 = jb + lg * 4;
    const int hwb = l15 * 256 + ((2 * j0) ^ ((l15 & 7) << 4));

    for (int tp = 0; tp < SEQ / 2; tp++) {
        // chunk gate (CH=8): next 8 steps prefetch h0 up to 2tp+9 -> flag >= tp/4 + 2
        if (tp && !(tp & 3)) {
            int need = tp / 4 + 2;
            wait_flag(flags, bblk, need > 64 ? 64 : need, tid);
        }
#pragma unroll
        for (int ph = 0; ph < 2; ph++) {            // static bank parity
            const int t = 2 * tp + ph;
            const uint8_t* hb = lds + ph * 4096;
            bf16x8 hf[4];
#pragma unroll
            for (int kt = 0; kt < 4; kt++) {
                int kb = (2 * (kt * 32 + lg * 8)) ^ swz;
                hf[kt] = *(const bf16x8*)(hb + l15 * 256 + kb);
            }
            if (t + 2 < SEQ) {
#pragma unroll
                for (int kt = 0; kt < 4; kt++) {
                    const bf16x8 v = *(const bf16x8*)(hseq + (gbase + (size_t)(t + 2) * 8192 + kt * 64) * 8);
                    if (ph == 0) h0B[kt] = v; else h0A[kt] = v;
                }
            }

            // 8 interleaved chains: g4 (on-path) + accn (off-path), kt-outer
            f32x4v g4[4], accn[4];
#pragma unroll
            for (int kt = 0; kt < 4; kt++) {
#pragma unroll
                for (int c = 0; c < 4; c++)
                    g4[c] = MFMA16(whh[c][kt], hf[kt], kt == 0 ? acc[c] : g4[c]);
#pragma unroll
                for (int c = 0; c < 4; c++) {
                    if (ph == 0)
                        accn[c] = MFMA16(wih[c][kt], h0A[kt], kt == 0 ? bias[c] : accn[c]);
                    else
                        accn[c] = MFMA16(wih[c][kt], h0B[kt], kt == 0 ? bias[c] : accn[c]);
                }
            }

            float h[4];
#pragma unroll
            for (int e = 0; e < 4; e++) {
                float ig = fsig(g4[0][e]);
                float fg = fsig(g4[1][e]);
                float gg = ftanh(g4[2][e]);
                float og = fsig(g4[3][e]);
                float cv = fg * cst[e] + ig * gg;
                cst[e] = cv;
                h[e] = og * ftanh(cv);
            }
            *(uint2*)(lds + (ph ^ 1) * 4096 + hwb) =
                make_uint2(bfp(h[0], h[1]), bfp(h[2], h[3]));
            if (ph == 1 && t == SEQ - 1)
                *(f32x4v*)(hfin + l15 * HID + j0) = f32x4v{h[0], h[1], h[2], h[3]};

            asm volatile("s_waitcnt lgkmcnt(0)\n\ts_barrier" ::: "memory");
#pragma unroll
            for (int c = 0; c < 4; c++) acc[c] = accn[c];
        }
    }
    __syncthreads();

    // fused FC: out[b][o] = relu(h1).fcw[o] + fcb[o]
    const int fb = tid >> 5, op = (tid & 31) * 2;
    float a0 = fcb[op], a1 = fcb[op + 1];
    const float4* w0 = (const float4*)(fcw + op * HID);
    const float4* w1 = (const float4*)(fcw + (op + 1) * HID);
    const float4* hv4 = (const float4*)(hfin + fb * HID);
#pragma unroll 8
    for (int k = 0; k < 32; k++) {
        float4 hv = hv4[k];
        float r0 = fmaxf(hv.x, 0.f), r1 = fmaxf(hv.y, 0.f);
        float r2 = fmaxf(hv.z, 0.f), r3 = fmaxf(hv.w, 0.f);
        float4 wa = w0[k], wb = w1[k];
        a0 += r0 * wa.x + r1 * wa.y + r2 * wa.z + r3 * wa.w;
        a1 += r0 * wb.x + r1 * wb.y + r2 * wb.z + r3 * wb.w;
    }
    out[(bb + fb) * 64 + op] = a0;
    out[(bb + fb) * 64 + op + 1] = a1;
}

// =============== single launch: blocks 0-31 = L0 producer, 32-63 = L1 consumer ===============
__global__ __launch_bounds__(512, 2) void lstm_pipe(
    const float* __restrict__ x,
    const float* __restrict__ Wih0, const float* __restrict__ Whh0,
    const float* __restrict__ bih0, const float* __restrict__ bhh0,
    const float* __restrict__ Wih1, const float* __restrict__ Whh1,
    const float* __restrict__ bih1, const float* __restrict__ bhh1,
    const float* __restrict__ fcw, const float* __restrict__ fcb,
    int* flags, unsigned short* hseq, float* __restrict__ out)
{
    __shared__ __align__(16) uint8_t lds[16384];
    if (blockIdx.x < 32) {
        l0_body(lds, x, Wih0, Whh0, bih0, bhh0, hseq, flags);
    } else {
        l1_body(lds, hseq, Wih1, Whh1, bih1, bhh1, fcw, fcb, out, flags);
    }
}

extern "C" void kernel_launch(void* const* d_in, const int* in_sizes, int n_in,
                              void* d_out, int out_size, void* d_ws, size_t ws_size,
                              hipStream_t stream) {
    const float* x    = (const float*)d_in[0];
    const float* Wih0 = (const float*)d_in[1];
    const float* Whh0 = (const float*)d_in[2];
    const float* bih0 = (const float*)d_in[3];
    const float* bhh0 = (const float*)d_in[4];
    const float* Wih1 = (const float*)d_in[5];
    const float* Whh1 = (const float*)d_in[6];
    const float* bih1 = (const float*)d_in[7];
    const float* bhh1 = (const float*)d_in[8];
    const float* fcw  = (const float*)d_in[9];
    const float* fcb  = (const float*)d_in[10];

    // ws: [0,4096) flags (zeroed per call), [4096, 4096+64MiB) hseq bf16 granules
    int* flags = (int*)d_ws;
    unsigned short* hseq = (unsigned short*)((char*)d_ws + 4096);
    hipMemsetAsync(d_ws, 0, 4096, stream);

    lstm_pipe<<<64, 512, 0, stream>>>(x, Wih0, Whh0, bih0, bhh0,
                                      Wih1, Whh1, bih1, bhh1, fcw, fcb,
                                      flags, hseq, (float*)d_out);
}